// Round 2
// baseline (279.893 us; speedup 1.0000x reference)
//
#include <hip/hip_runtime.h>

typedef unsigned short u16;
typedef unsigned int u32;
typedef __bf16 bf16x8 __attribute__((ext_vector_type(8)));
typedef float f32x4 __attribute__((ext_vector_type(4)));
typedef u16 u16x8 __attribute__((ext_vector_type(8)));

__device__ __forceinline__ float bf2f(u16 u) {
    u32 i = ((u32)u) << 16;
    float f;
    __builtin_memcpy(&f, &i, 4);
    return f;
}
__device__ __forceinline__ u16 f2bf(float f) {
    u32 i;
    __builtin_memcpy(&i, &f, 4);
    i += 0x7fffu + ((i >> 16) & 1u);
    return (u16)(i >> 16);
}
__device__ __forceinline__ float sigm(float x) { return 1.0f / (1.0f + __expf(-x)); }
__device__ __forceinline__ float tanh_f(float x) { return 1.0f - 2.0f / (__expf(2.0f * x) + 1.0f); }

template <bool F32>
__device__ __forceinline__ float ld1(const void* p, size_t i) {
    if (F32) return ((const float*)p)[i];
    return bf2f(((const u16*)p)[i]);
}

// ---- dtype detector -------------------------------------------------------
// Classifies x: bf16 pairs -> both u16 halves have plausible exponents;
// fp32 -> low half is mantissa bits (uniform) and usually fails.
__global__ void k_detect(const u32* __restrict__ x, int* __restrict__ flag) {
    __shared__ int cnt;
    if (threadIdx.x == 0) cnt = 0;
    __syncthreads();
    int c = 0;
#pragma unroll
    for (int i = 0; i < 4; i++) {
        u32 w = x[threadIdx.x * 4 + i];
        u32 lo = w & 0xffffu, hi = w >> 16;
        u32 e0 = (lo >> 7) & 0xffu, e1 = (hi >> 7) & 0xffu;
        int ok = (e0 == 0 || (e0 >= 0x60 && e0 <= 0x90)) &&
                 (e1 == 0 || (e1 >= 0x60 && e1 <= 0x90));
        c += ok;
    }
    atomicAdd(&cnt, c);
    __syncthreads();
    if (threadIdx.x == 0) *flag = (cnt >= 512) ? 1 : 0;  // 1 = bf16 inputs
}

// ---- LDS staging (reg-staged, padded rows, no swizzle) --------------------
// LDS tile: [ROWS][72] u16 (row stride 144B, 16B-aligned slots).
// Thread t stages (row = i*32 + (t>>3), slot = t&7) of a ROWSx64 k-tile.
template <bool F32, int ROWS>
__device__ __forceinline__ void stage(const void* __restrict__ g, int row0, int kb,
                                      u16* __restrict__ s, int tid) {
    const int slot = tid & 7, rr = tid >> 3;
#pragma unroll
    for (int i = 0; i < ROWS / 32; i++) {
        const int row = i * 32 + rr;
        const size_t goff = (size_t)(row0 + row) * 512 + kb + slot * 8;
        u16x8 v;
        if (F32) {
            const float* gp = (const float*)g + goff;
            f32x4 a = *(const f32x4*)gp;
            f32x4 b = *(const f32x4*)(gp + 4);
#pragma unroll
            for (int j = 0; j < 4; j++) { v[j] = f2bf(a[j]); v[4 + j] = f2bf(b[j]); }
        } else {
            v = *(const u16x8*)((const u16*)g + goff);
        }
        *(u16x8*)(s + row * 72 + slot * 8) = v;
    }
}

// A/B fragment for mfma_f32_16x16x32_bf16: lane holds row=(lane&15),
// k = (lane>>4)*8 + j (8 contiguous bf16 -> one ds_read_b128).
__device__ __forceinline__ bf16x8 ldfrag(const u16* s, int rbase, int kk, int lane) {
    return *(const bf16x8*)(s + (rbase + (lane & 15)) * 72 + ((kk >> 3) + (lane >> 4)) * 8);
}

// ---- kernel: h_sum (always writes bf16 to ws) -----------------------------
template <bool F32>
__global__ __launch_bounds__(256) void k_hsum(const void* __restrict__ ch, u16* __restrict__ hs,
                                              const int* __restrict__ flag) {
    if ((*flag != 0) == F32) return;
    size_t e = ((size_t)blockIdx.x * 256 + threadIdx.x) * 8;
    float s[8] = {0.f, 0.f, 0.f, 0.f, 0.f, 0.f, 0.f, 0.f};
#pragma unroll
    for (int k = 0; k < 8; k++) {
        size_t koff = (size_t)k * 4194304 + e;
        if (F32) {
            f32x4 a = *(const f32x4*)((const float*)ch + koff);
            f32x4 b = *(const f32x4*)((const float*)ch + koff + 4);
#pragma unroll
            for (int j = 0; j < 4; j++) { s[j] += a[j]; s[4 + j] += b[j]; }
        } else {
            u16x8 v = *(const u16x8*)((const u16*)ch + koff);
#pragma unroll
            for (int j = 0; j < 8; j++) s[j] += bf2f(v[j]);
        }
    }
    u16x8 o;
#pragma unroll
    for (int j = 0; j < 8; j++) o[j] = f2bf(s[j]);
    *(u16x8*)(hs + e) = o;
}

// ---- kernel: gate pre-activations (bf16 pre-acts to ws) -------------------
// grid (64, 16): x = M-tile (128 rows), y: gate = y>>2, col0 = (y&3)*128.
template <bool F32>
__global__ __launch_bounds__(256) void k_gates(
    const void* __restrict__ x, const u16* __restrict__ hsum,
    const void* __restrict__ Wi, const void* __restrict__ bi, const void* __restrict__ Ui,
    const void* __restrict__ Wf, const void* __restrict__ bf_,
    const void* __restrict__ Wo, const void* __restrict__ bo, const void* __restrict__ Uo,
    const void* __restrict__ Wu, const void* __restrict__ bu, const void* __restrict__ Uu,
    u16* __restrict__ pre_i, u16* __restrict__ pre_f,
    u16* __restrict__ pre_o, u16* __restrict__ pre_u,
    const int* __restrict__ flag) {
    if ((*flag != 0) == F32) return;
    __shared__ __attribute__((aligned(16))) u16 sA[128 * 72];
    __shared__ __attribute__((aligned(16))) u16 sB[128 * 72];
    const int tid = threadIdx.x, lane = tid & 63, wave = tid >> 6;
    const int gate = blockIdx.y >> 2, col0 = (blockIdx.y & 3) * 128, row0 = blockIdx.x * 128;

    const void *Wp, *Up = nullptr, *bp;
    u16* ob;
    if (gate == 0) { Wp = Wi; Up = Ui; bp = bi; ob = pre_i; }
    else if (gate == 1) { Wp = Wf; bp = bf_; ob = pre_f; }
    else if (gate == 2) { Wp = Wo; Up = Uo; bp = bo; ob = pre_o; }
    else { Wp = Wu; Up = Uu; bp = bu; ob = pre_u; }

    const int wrow = (wave >> 1) * 64, wcol = (wave & 1) * 64;
    f32x4 acc[4][4];
#pragma unroll
    for (int m = 0; m < 4; m++)
#pragma unroll
        for (int n = 0; n < 4; n++) acc[m][n] = (f32x4){0.f, 0.f, 0.f, 0.f};

    // phase 0: x @ W^T ; phase 1 (if Up): hsum @ U^T  (hsum is ALWAYS bf16)
    for (int ph = 0; ph < 2; ++ph) {
        if (ph == 1 && !Up) break;
#pragma unroll 1
        for (int ks = 0; ks < 8; ++ks) {
            if (ph == 0) {
                stage<F32, 128>(x, row0, ks * 64, sA, tid);
                stage<F32, 128>(Wp, col0, ks * 64, sB, tid);
            } else {
                stage<false, 128>(hsum, row0, ks * 64, sA, tid);
                stage<F32, 128>(Up, col0, ks * 64, sB, tid);
            }
            __syncthreads();
#pragma unroll
            for (int kk = 0; kk < 64; kk += 32) {
                bf16x8 a[4], b[4];
#pragma unroll
                for (int m = 0; m < 4; m++) a[m] = ldfrag(sA, wrow + m * 16, kk, lane);
#pragma unroll
                for (int n = 0; n < 4; n++) b[n] = ldfrag(sB, wcol + n * 16, kk, lane);
#pragma unroll
                for (int m = 0; m < 4; m++)
#pragma unroll
                    for (int n = 0; n < 4; n++)
                        acc[m][n] = __builtin_amdgcn_mfma_f32_16x16x32_bf16(a[m], b[n], acc[m][n], 0, 0, 0);
            }
            __syncthreads();
        }
    }

    // epilogue: + bias, store bf16 pre-activation
#pragma unroll
    for (int n = 0; n < 4; n++) {
        float bv = ld1<F32>(bp, col0 + wcol + n * 16 + (lane & 15));
#pragma unroll
        for (int m = 0; m < 4; m++)
#pragma unroll
            for (int r = 0; r < 4; r++) {
                int row = row0 + wrow + m * 16 + ((lane >> 4) << 2) + r;
                int col = col0 + wcol + n * 16 + (lane & 15);
                ob[(size_t)row * 512 + col] = f2bf(acc[m][n][r] + bv);
            }
    }
}

// ---- kernel: combine i,o,u in-place (ws only; dtype-independent) ----------
// pre_i <- sigm(pre_i)*tanh(pre_u);  pre_o <- sigm(pre_o)
__global__ __launch_bounds__(256) void k_combine(u16* __restrict__ pi, u16* __restrict__ po,
                                                 const u16* __restrict__ pu) {
    size_t e = ((size_t)blockIdx.x * 256 + threadIdx.x) * 8;
    u16x8 vi = *(u16x8*)(pi + e), vo = *(u16x8*)(po + e), vu = *(const u16x8*)(pu + e);
#pragma unroll
    for (int j = 0; j < 8; j++) {
        vi[j] = f2bf(sigm(bf2f(vi[j])) * tanh_f(bf2f(vu[j])));
        vo[j] = f2bf(sigm(bf2f(vo[j])));
    }
    *(u16x8*)(pi + e) = vi;
    *(u16x8*)(po + e) = vo;
}

// ---- kernel: per-child forget GEMMs + fused cell update -------------------
// grid (128, 4): 64-row x 128-col output tiles.
template <bool F32>
__global__ __launch_bounds__(256) void k_children(
    const void* __restrict__ child_h, const void* __restrict__ child_c,
    const void* __restrict__ Uf, const u16* __restrict__ pre_f,
    const u16* __restrict__ iu, const u16* __restrict__ og,
    void* __restrict__ out, const int* __restrict__ flag) {
    if ((*flag != 0) == F32) return;
    __shared__ __attribute__((aligned(16))) u16 sA[64 * 72];
    __shared__ __attribute__((aligned(16))) u16 sB[128 * 72];
    const int tid = threadIdx.x, lane = tid & 63, wave = tid >> 6;
    const int row0 = blockIdx.x * 64, col0 = blockIdx.y * 128;
    const int wrow = (wave >> 1) * 32, wcol = (wave & 1) * 64;

    // cache wfx (= pre_f) tile in fragment layout, packed 2x bf16 per u32
    u32 wfxp[2][4][2];
#pragma unroll
    for (int m = 0; m < 2; m++)
#pragma unroll
        for (int n = 0; n < 4; n++)
#pragma unroll
            for (int rp = 0; rp < 2; rp++) {
                int row = row0 + wrow + m * 16 + ((lane >> 4) << 2) + rp * 2;
                int col = col0 + wcol + n * 16 + (lane & 15);
                u32 u0 = pre_f[(size_t)row * 512 + col];
                u32 u1 = pre_f[(size_t)(row + 1) * 512 + col];
                wfxp[m][n][rp] = u0 | (u1 << 16);
            }

    f32x4 cacc[2][4];
#pragma unroll
    for (int m = 0; m < 2; m++)
#pragma unroll
        for (int n = 0; n < 4; n++) cacc[m][n] = (f32x4){0.f, 0.f, 0.f, 0.f};

#pragma unroll 1
    for (int k = 0; k < 8; k++) {
        f32x4 gacc[2][4];
#pragma unroll
        for (int m = 0; m < 2; m++)
#pragma unroll
            for (int n = 0; n < 4; n++)
#pragma unroll
                for (int r = 0; r < 4; r++)
                    gacc[m][n][r] = bf2f((u16)((wfxp[m][n][r >> 1] >> ((r & 1) * 16)) & 0xffffu));

        const void* Ah = F32 ? (const void*)((const float*)child_h + (size_t)k * 4194304)
                             : (const void*)((const u16*)child_h + (size_t)k * 4194304);
#pragma unroll 1
        for (int ks = 0; ks < 8; ++ks) {
            stage<F32, 64>(Ah, row0, ks * 64, sA, tid);
            stage<F32, 128>(Uf, col0, ks * 64, sB, tid);
            __syncthreads();
#pragma unroll
            for (int kk = 0; kk < 64; kk += 32) {
                bf16x8 a[2], b[4];
#pragma unroll
                for (int m = 0; m < 2; m++) a[m] = ldfrag(sA, wrow + m * 16, kk, lane);
#pragma unroll
                for (int n = 0; n < 4; n++) b[n] = ldfrag(sB, wcol + n * 16, kk, lane);
#pragma unroll
                for (int m = 0; m < 2; m++)
#pragma unroll
                    for (int n = 0; n < 4; n++)
                        gacc[m][n] = __builtin_amdgcn_mfma_f32_16x16x32_bf16(a[m], b[n], gacc[m][n], 0, 0, 0);
            }
            __syncthreads();
        }

#pragma unroll
        for (int m = 0; m < 2; m++)
#pragma unroll
            for (int n = 0; n < 4; n++)
#pragma unroll
                for (int r = 0; r < 4; r++) {
                    int row = row0 + wrow + m * 16 + ((lane >> 4) << 2) + r;
                    int col = col0 + wcol + n * 16 + (lane & 15);
                    float f = sigm(gacc[m][n][r]);
                    cacc[m][n][r] += f * ld1<F32>(child_c, (size_t)k * 4194304 + (size_t)row * 512 + col);
                }
    }

    // fused cell update epilogue
#pragma unroll
    for (int m = 0; m < 2; m++)
#pragma unroll
        for (int n = 0; n < 4; n++)
#pragma unroll
            for (int r = 0; r < 4; r++) {
                int row = row0 + wrow + m * 16 + ((lane >> 4) << 2) + r;
                int col = col0 + wcol + n * 16 + (lane & 15);
                size_t idx = (size_t)row * 512 + col;
                float c = bf2f(iu[idx]) + cacc[m][n][r];
                float h = bf2f(og[idx]) * tanh_f(c);
                if (F32) {
                    ((float*)out)[idx] = h;
                    ((float*)out)[4194304 + idx] = c;
                } else {
                    ((u16*)out)[idx] = f2bf(h);
                    ((u16*)out)[4194304 + idx] = f2bf(c);
                }
            }
}

extern "C" void kernel_launch(void* const* d_in, const int* in_sizes, int n_in,
                              void* d_out, int out_size, void* d_ws, size_t ws_size,
                              hipStream_t stream) {
    const void* x  = d_in[0];
    const void* ch = d_in[1];
    const void* cc = d_in[2];
    const void* Wi = d_in[3];
    const void* bi = d_in[4];
    const void* Ui = d_in[5];
    const void* Wf = d_in[6];
    const void* bf_ = d_in[7];
    const void* Uf = d_in[8];
    const void* Wo = d_in[9];
    const void* bo = d_in[10];
    const void* Uo = d_in[11];
    const void* Wu = d_in[12];
    const void* bu = d_in[13];
    const void* Uu = d_in[14];

    char* ws = (char*)d_ws;
    int* flag   = (int*)ws;
    u16* hsum   = (u16*)(ws + 256);
    u16* pre_i  = (u16*)(ws + 256 + 8388608ull * 1);
    u16* pre_o  = (u16*)(ws + 256 + 8388608ull * 2);
    u16* pre_u  = (u16*)(ws + 256 + 8388608ull * 3);
    u16* pre_f  = (u16*)(ws + 256 + 8388608ull * 4);  // end ~40 MiB

    k_detect<<<1, 256, 0, stream>>>((const u32*)x, flag);

    k_hsum<false><<<2048, 256, 0, stream>>>(ch, hsum, flag);
    k_hsum<true><<<2048, 256, 0, stream>>>(ch, hsum, flag);

    k_gates<false><<<dim3(64, 16), 256, 0, stream>>>(x, hsum, Wi, bi, Ui, Wf, bf_,
                                                     Wo, bo, Uo, Wu, bu, Uu,
                                                     pre_i, pre_f, pre_o, pre_u, flag);
    k_gates<true><<<dim3(64, 16), 256, 0, stream>>>(x, hsum, Wi, bi, Ui, Wf, bf_,
                                                    Wo, bo, Uo, Wu, bu, Uu,
                                                    pre_i, pre_f, pre_o, pre_u, flag);

    k_combine<<<2048, 256, 0, stream>>>(pre_i, pre_o, pre_u);

    k_children<false><<<dim3(128, 4), 256, 0, stream>>>(ch, cc, Uf, pre_f, pre_i, pre_o,
                                                        d_out, flag);
    k_children<true><<<dim3(128, 4), 256, 0, stream>>>(ch, cc, Uf, pre_f, pre_i, pre_o,
                                                       d_out, flag);
}